// Round 9
// baseline (818.303 us; speedup 1.0000x reference)
//
#include <hip/hip_runtime.h>

typedef __attribute__((ext_vector_type(8))) short short8;
typedef __attribute__((ext_vector_type(4))) float f32x4;
typedef unsigned short u16;

#define DEVI static __device__ __forceinline__

DEVI float bf2f(u16 u) {
    unsigned int x = ((unsigned int)u) << 16;
    float f;
    __builtin_memcpy(&f, &x, 4);
    return f;
}
DEVI u16 f2bf(float f) {
    unsigned int x;
    __builtin_memcpy(&x, &f, 4);
    unsigned int r = x + 0x7fffu + ((x >> 16) & 1u);
    return (u16)(r >> 16);
}

// ---------------- W f32 -> bf16 (with K padding to Kp) ----------------
__global__ __launch_bounds__(256) void convert_w_kernel(
    const float* __restrict__ wsrc, u16* __restrict__ wdst,
    int K, int Kp, long total_elems)
{
    long idx = (long)blockIdx.x * 256 + threadIdx.x;
    const long stride = (long)gridDim.x * 256;
    for (; idx < total_elems; idx += stride) {
        long rw = idx / Kp;
        int col = (int)(idx - rw * Kp);
        float v = (col < K) ? wsrc[rw * K + col] : 0.f;
        wdst[idx] = f2bf(v);
    }
}

// ------- row L2-normalize x0 (f32, K cols) -> bf16 (Kp cols, zero pad) -------
__global__ __launch_bounds__(256) void norm_x0_kernel(
    const float* __restrict__ x, u16* __restrict__ outp, int K, int Kp)
{
    const int row = blockIdx.x;
    const float* xr = x + (size_t)row * K;
    float ss = 0.f;
    for (int c = threadIdx.x; c < K; c += 256) { float v = xr[c]; ss += v * v; }
#pragma unroll
    for (int off = 32; off; off >>= 1) ss += __shfl_xor(ss, off);
    __shared__ float red[4];
    if ((threadIdx.x & 63) == 0) red[threadIdx.x >> 6] = ss;
    __syncthreads();
    const float tot = red[0] + red[1] + red[2] + red[3];
    const float scale = 1.f / (sqrtf(tot) + 1e-4f);
    u16* orow = outp + (size_t)row * Kp;
    for (int c = threadIdx.x; c < Kp; c += 256)
        orow[c] = f2bf(c < K ? xr[c] * scale : 0.f);
}

// ============ 256x256 GEMM + fused epilogue ============
// MODE 0: v=relu(acc+b); write C; total_p = partial; ss_p = partial
// MODE 1: v=relu(s*acc+b); write C; total_p += partial; ss_p = partial
// MODE 2: v=relu(s*acc+b); NO C;    total_p += partial
// Partials are per-(slot=tn*4+wc) -> deterministic, class-symmetric sums.

#define AS1G const __attribute__((address_space(1))) void*
#define AS3L __attribute__((address_space(3))) void*

#define STAGE_A(s_, h_) do {                                                     \
    const int sd_ = (s_) & 1; const size_t ko_ = (size_t)(s_) << 6;              \
    _Pragma("unroll") for (int i_ = 0; i_ < 2; ++i_)                             \
        __builtin_amdgcn_global_load_lds(                                        \
            (AS1G)(pA + (size_t)((h_) * 128 + i_ * 64) * K + ko_),               \
            (AS3L)&ldsA[sd_ * 16384 + (h_) * 8192 + i_ * 4096 + w * 512],        \
            16, 0, 0);                                                           \
} while (0)

#define STAGE_B(s_, h_) do {                                                     \
    const int sd_ = (s_) & 1; const size_t ko_ = (size_t)(s_) << 6;              \
    _Pragma("unroll") for (int i_ = 0; i_ < 2; ++i_)                             \
        __builtin_amdgcn_global_load_lds(                                        \
            (AS1G)(pB + (size_t)((h_) * 128 + i_ * 64) * K + ko_),               \
            (AS3L)&ldsB[sd_ * 16384 + (h_) * 8192 + i_ * 4096 + w * 512],        \
            16, 0, 0);                                                           \
} while (0)

#define READ_A(qm_)                                                              \
    _Pragma("unroll") for (int i2_ = 0; i2_ < 4; ++i2_)                          \
    _Pragma("unroll") for (int kk_ = 0; kk_ < 2; ++kk_)                          \
        a_[i2_][kk_] = *(const short8*)&ldsA[d * 16384 + (qm_) * 8192 +          \
            (wr * 64 + i2_ * 16 + rsel) * 64 + ((((kk_ << 2) + hi) ^ lsw) << 3)]

#define READ_B(qn_, bb_)                                                         \
    _Pragma("unroll") for (int j2_ = 0; j2_ < 2; ++j2_)                          \
    _Pragma("unroll") for (int kk_ = 0; kk_ < 2; ++kk_)                          \
        bb_[j2_][kk_] = *(const short8*)&ldsB[d * 16384 + (qn_) * 8192 +         \
            (wc * 32 + j2_ * 16 + rsel) * 64 + ((((kk_ << 2) + hi) ^ lsw) << 3)]

#define MFMA_Q(qm_, qn_, bb_)                                                    \
    _Pragma("unroll") for (int i2_ = 0; i2_ < 4; ++i2_)                          \
    _Pragma("unroll") for (int j2_ = 0; j2_ < 2; ++j2_)                          \
    _Pragma("unroll") for (int kk_ = 0; kk_ < 2; ++kk_)                          \
        acc[(qm_) * 4 + i2_][(qn_) * 2 + j2_] =                                  \
            __builtin_amdgcn_mfma_f32_16x16x32_bf16(                             \
                a_[i2_][kk_], bb_[j2_][kk_],                                     \
                acc[(qm_) * 4 + i2_][(qn_) * 2 + j2_], 0, 0, 0)

#define PH_TAIL(mq_)                                                             \
    asm volatile("s_waitcnt lgkmcnt(0)" ::: "memory");                           \
    __builtin_amdgcn_sched_barrier(0);                                           \
    __builtin_amdgcn_s_setprio(1);                                               \
    mq_;                                                                         \
    __builtin_amdgcn_s_setprio(0);                                               \
    __builtin_amdgcn_s_barrier()

template<int MODE>
__global__ __launch_bounds__(512, 2) void gemm256_fused(
    const u16* __restrict__ A, const u16* __restrict__ W,
    const float* __restrict__ bias, const float* __restrict__ hmat,
    const float* __restrict__ srow, u16* __restrict__ C,
    float* __restrict__ total_p, float* __restrict__ ss_p,
    int N, int K)
{
    __shared__ __align__(16) u16 ldsA[2 * 2 * 128 * 64];  // [dbuf][half][128][64]
    __shared__ __align__(16) u16 ldsB[2 * 2 * 128 * 64];
    __shared__ float s_lds[256];

    const int tid = threadIdx.x;
    const int lane = tid & 63;
    const int w = tid >> 6;               // wave 0..7
    const int wr = w >> 2, wc = w & 3;    // 2M x 4N wave grid
    const int rsel = lane & 15, hi = lane >> 4, lsw = lane & 7;

    // T1: XCD-aware bijective swizzle (grid % 8 == 0)
    int bid = blockIdx.x;
    const int cpx = gridDim.x >> 3;
    bid = (bid & 7) * cpx + (bid >> 3);
    const int ntn = N >> 8;
    const int tm = bid / ntn, tn = bid - tm * ntn;
    const size_t m0 = (size_t)tm << 8, n0 = (size_t)tn << 8;

    const int NS = K >> 6;

    const int srow_t = tid >> 3;
    const int scol = ((tid & 7) ^ (srow_t & 7)) << 3;
    const u16* pA = A + (m0 + srow_t) * (size_t)K + scol;
    const u16* pB = W + (n0 + srow_t) * (size_t)K + scol;

    f32x4 acc[8][4] = {};
    short8 a_[4][2], bA[2][2], bB[2][2];

    if (MODE != 0) { if (tid < 256) s_lds[tid] = srow[m0 + tid]; }

    // prologue: full tile 0, in consumption order; keep Bh1,Ah1 in flight.
    STAGE_A(0, 0); STAGE_B(0, 0); STAGE_B(0, 1); STAGE_A(0, 1);
    asm volatile("s_waitcnt vmcnt(4)" ::: "memory");
    __builtin_amdgcn_s_barrier();
    __builtin_amdgcn_sched_barrier(0);

    for (int s = 0; s < NS; ++s) {
        const int d = s & 1;
        const bool pf = (s + 1 < NS);

        // ---- ph0: quadrant (0,0) ----
        READ_A(0);
        READ_B(0, bA);
        if (pf) {
            STAGE_A(s + 1, 0);
            asm volatile("s_waitcnt vmcnt(4)" ::: "memory");
        } else {
            asm volatile("s_waitcnt vmcnt(2)" ::: "memory");
        }
        __builtin_amdgcn_s_barrier();
        PH_TAIL(MFMA_Q(0, 0, bA));

        // ---- ph1: quadrant (0,1) ----
        READ_B(1, bB);
        if (pf) {
            STAGE_B(s + 1, 0);
            asm volatile("s_waitcnt vmcnt(4)" ::: "memory");
        } else {
            asm volatile("s_waitcnt vmcnt(0)" ::: "memory");
        }
        __builtin_amdgcn_s_barrier();
        PH_TAIL(MFMA_Q(0, 1, bB));

        // ---- ph2: quadrant (1,0) ----
        READ_A(1);
        if (pf) STAGE_B(s + 1, 1);
        __builtin_amdgcn_s_barrier();
        PH_TAIL(MFMA_Q(1, 0, bA));

        // ---- ph3: quadrant (1,1) ----
        if (pf) {
            STAGE_A(s + 1, 1);
            asm volatile("s_waitcnt vmcnt(4)" ::: "memory");
        }
        __builtin_amdgcn_s_barrier();
        __builtin_amdgcn_sched_barrier(0);
        __builtin_amdgcn_s_setprio(1);
        MFMA_Q(1, 1, bB);
        __builtin_amdgcn_s_setprio(0);
        __builtin_amdgcn_s_barrier();
    }

    // ---- epilogue (1): in-place v = relu(s*acc + b) ----
    float bv[4];
#pragma unroll
    for (int j = 0; j < 4; ++j)
        bv[j] = bias[n0 + (j >> 1) * 128 + wc * 32 + (j & 1) * 16 + rsel];
#pragma unroll
    for (int i = 0; i < 8; ++i) {
#pragma unroll
        for (int rg = 0; rg < 4; ++rg) {
            float sv = 1.f;
            if (MODE != 0) sv = s_lds[(i >> 2) * 128 + wr * 64 + (i & 3) * 16 + hi * 4 + rg];
#pragma unroll
            for (int j = 0; j < 4; ++j) {
                float v = acc[i][j][rg] * sv + bv[j];
                acc[i][j][rg] = v > 0.f ? v : 0.f;
            }
        }
    }

    // ---- epilogue (2): goodness + ss partials (deterministic per-slot) ----
    float hreg[10][4];
#pragma unroll
    for (int c = 0; c < 10; ++c)
#pragma unroll
        for (int j = 0; j < 4; ++j)
            hreg[c][j] = hmat[c * 2048 + n0 + (j >> 1) * 128 + wc * 32 + (j & 1) * 16 + rsel];
    const int slot = tn * 4 + wc;
#pragma unroll
    for (int i = 0; i < 8; ++i) {
#pragma unroll
        for (int rg = 0; rg < 4; ++rg) {
            float p[11];
#pragma unroll
            for (int c = 0; c < 10; ++c) {
                float a = acc[i][0][rg] * hreg[c][0];
                a += acc[i][1][rg] * hreg[c][1];
                a += acc[i][2][rg] * hreg[c][2];
                a += acc[i][3][rg] * hreg[c][3];
                p[c] = a;
            }
            p[10] = acc[i][0][rg] * acc[i][0][rg] + acc[i][1][rg] * acc[i][1][rg]
                  + acc[i][2][rg] * acc[i][2][rg] + acc[i][3][rg] * acc[i][3][rg];
            const int nred = (MODE < 2) ? 11 : 10;
#pragma unroll
            for (int m = 1; m < 16; m <<= 1) {
#pragma unroll
                for (int c = 0; c < 11; ++c)
                    if (c < nred) p[c] += __shfl_xor(p[c], m);
            }
            if (rsel == 0) {
                const int grow = (int)m0 + (i >> 2) * 128 + wr * 64 + (i & 3) * 16 + hi * 4 + rg;
                float* tp = total_p + ((size_t)slot * 16384 + grow) * 10;
#pragma unroll
                for (int c = 0; c < 10; ++c) {
                    if (MODE == 0) tp[c] = p[c]; else tp[c] += p[c];
                }
                if (MODE < 2) ss_p[(size_t)slot * 16384 + grow] = p[10];
            }
        }
    }

    // ---- epilogue (3): repack via own 16KB LDS region, coalesced C store ----
    if (MODE < 2) {
        u16* ep = (w < 4) ? &ldsA[w * 8192] : &ldsB[(w - 4) * 8192];
#pragma unroll
        for (int j = 0; j < 4; ++j) {
            const int lc = (j >> 1) * 32 + (j & 1) * 16 + rsel;
            const int slt = lc >> 3, cb = lc & 7;
#pragma unroll
            for (int i = 0; i < 8; ++i) {
                const int lrb = (i >> 2) * 64 + (i & 3) * 16 + hi * 4;
#pragma unroll
                for (int rg = 0; rg < 4; ++rg) {
                    const int lr = lrb + rg;
                    ep[lr * 64 + ((slt ^ (lr & 7)) << 3) + cb] = f2bf(acc[i][j][rg]);
                }
            }
        }
        asm volatile("s_waitcnt lgkmcnt(0)" ::: "memory");
        const int sl = lane & 7;
#pragma unroll
        for (int it2 = 0; it2 < 16; ++it2) {
            const int r = it2 * 8 + (lane >> 3);
            short8 vv = *(const short8*)&ep[r * 64 + ((sl ^ (r & 7)) << 3)];
            const size_t gr = m0 + (size_t)((r >> 6) * 128 + wr * 64 + (r & 63));
            const size_t gc = n0 + (size_t)((sl >> 2) * 128 + wc * 32 + (sl & 3) * 8);
            *(short8*)&C[gr * (size_t)N + gc] = vv;
        }
    }
}

// ---------------- s[r] = 1/(sqrt(sum_slots ss_p)+eps) ----------------
__global__ __launch_bounds__(256) void reduce_s_kernel(
    const float* __restrict__ ss_p, float* __restrict__ s)
{
    const int r = blockIdx.x * 256 + threadIdx.x;
    float a = 0.f;
#pragma unroll
    for (int slot = 0; slot < 32; ++slot) a += ss_p[(size_t)slot * 16384 + r];
    s[r] = 1.f / (sqrtf(a) + 1e-4f);
}

// ---------------- argmax over summed class partials ----------------
__global__ __launch_bounds__(256) void argmax_kernel(
    const float* __restrict__ total_p, int* __restrict__ outp)
{
    const int r = blockIdx.x * 256 + threadIdx.x;
    float cls[10];
#pragma unroll
    for (int c = 0; c < 10; ++c) cls[c] = 0.f;
    for (int slot = 0; slot < 32; ++slot) {
        const float* tp = total_p + ((size_t)slot * 16384 + r) * 10;
#pragma unroll
        for (int c = 0; c < 10; ++c) cls[c] += tp[c];
    }
    float best = -3.4e38f;
    int bi = 0;
#pragma unroll
    for (int c = 0; c < 10; ++c) {
        if (cls[c] > best) { best = cls[c]; bi = c; }  // strict > : ties -> lowest
    }
    outp[r] = bi;
}

extern "C" void kernel_launch(void* const* d_in, const int* in_sizes, int n_in,
                              void* d_out, int out_size, void* d_ws, size_t ws_size,
                              hipStream_t stream)
{
    const float* x  = (const float*)d_in[0];
    const float* W0 = (const float*)d_in[1];
    const float* b0 = (const float*)d_in[2];
    const float* h0 = (const float*)d_in[3];
    const float* W1 = (const float*)d_in[4];
    const float* b1 = (const float*)d_in[5];
    const float* h1 = (const float*)d_in[6];
    const float* W2 = (const float*)d_in[7];
    const float* b2 = (const float*)d_in[8];
    const float* h2 = (const float*)d_in[9];
    int* out = (int*)d_out;

    const int M = 16384, N = 2048, K0 = 784, Kp0 = 896, D = 2048;

    char* ws = (char*)d_ws;
    size_t off = 0;
    auto alloc = [&](size_t bytes) -> void* {
        void* p = ws + off;
        off += (bytes + 255) & ~(size_t)255;
        return p;
    };
    u16* buf1  = (u16*)alloc((size_t)M * D * 2);     // x1 (layer-0 output)
    u16* buf2  = (u16*)alloc((size_t)M * D * 2);     // A0p, then x2
    u16* W0p   = (u16*)alloc((size_t)N * Kp0 * 2);
    u16* W1b   = (u16*)alloc((size_t)N * D * 2);
    u16* W2b   = (u16*)alloc((size_t)N * D * 2);
    float* total_p = (float*)alloc((size_t)32 * M * 10 * 4);  // 21 MB
    float* ss_p    = (float*)alloc((size_t)32 * M * 4);       // 2 MB
    float* svec    = (float*)alloc((size_t)M * 4);
    u16* A0p = buf2;  // 896-stride rows fit inside 2048-stride buffer

    convert_w_kernel<<<2048, 256, 0, stream>>>(W0, W0p, K0, Kp0, (long)N * Kp0);
    convert_w_kernel<<<2048, 256, 0, stream>>>(W1, W1b, D, D, (long)N * D);
    convert_w_kernel<<<2048, 256, 0, stream>>>(W2, W2b, D, D, (long)N * D);

    norm_x0_kernel<<<M, 256, 0, stream>>>(x, A0p, K0, Kp0);

    const int g256 = (M / 256) * (N / 256);  // 512 blocks, %8 == 0
    gemm256_fused<0><<<g256, 512, 0, stream>>>(A0p, W0p, b0, h0, nullptr, buf1,
                                               total_p, ss_p, N, Kp0);
    reduce_s_kernel<<<M / 256, 256, 0, stream>>>(ss_p, svec);
    gemm256_fused<1><<<g256, 512, 0, stream>>>(buf1, W1b, b1, h1, svec, buf2,
                                               total_p, ss_p, N, D);
    reduce_s_kernel<<<M / 256, 256, 0, stream>>>(ss_p, svec);
    gemm256_fused<2><<<g256, 512, 0, stream>>>(buf2, W2b, b2, h2, svec, nullptr,
                                               total_p, nullptr, N, D);
    argmax_kernel<<<M / 256, 256, 0, stream>>>(total_p, out);
}

// Round 10
// 674.468 us; speedup vs baseline: 1.2133x; 1.2133x over previous
//
#include <hip/hip_runtime.h>

typedef __attribute__((ext_vector_type(8))) short short8;
typedef __attribute__((ext_vector_type(4))) float f32x4;
typedef unsigned short u16;

#define DEVI static __device__ __forceinline__

DEVI float bf2f(u16 u) {
    unsigned int x = ((unsigned int)u) << 16;
    float f;
    __builtin_memcpy(&f, &x, 4);
    return f;
}
DEVI u16 f2bf(float f) {
    unsigned int x;
    __builtin_memcpy(&x, &f, 4);
    unsigned int r = x + 0x7fffu + ((x >> 16) & 1u);
    return (u16)(r >> 16);
}

// ---------------- W f32 -> bf16 (with K padding to Kp) ----------------
__global__ __launch_bounds__(256) void convert_w_kernel(
    const float* __restrict__ wsrc, u16* __restrict__ wdst,
    int K, int Kp, long total_elems)
{
    long idx = (long)blockIdx.x * 256 + threadIdx.x;
    const long stride = (long)gridDim.x * 256;
    for (; idx < total_elems; idx += stride) {
        long rw = idx / Kp;
        int col = (int)(idx - rw * Kp);
        float v = (col < K) ? wsrc[rw * K + col] : 0.f;
        wdst[idx] = f2bf(v);
    }
}

// ------- row L2-normalize x0 (f32, K cols) -> bf16 (Kp cols, zero pad) -------
__global__ __launch_bounds__(256) void norm_x0_kernel(
    const float* __restrict__ x, u16* __restrict__ outp, int K, int Kp)
{
    const int row = blockIdx.x;
    const float* xr = x + (size_t)row * K;
    float ss = 0.f;
    for (int c = threadIdx.x; c < K; c += 256) { float v = xr[c]; ss += v * v; }
#pragma unroll
    for (int off = 32; off; off >>= 1) ss += __shfl_xor(ss, off);
    __shared__ float red[4];
    if ((threadIdx.x & 63) == 0) red[threadIdx.x >> 6] = ss;
    __syncthreads();
    const float tot = red[0] + red[1] + red[2] + red[3];
    const float scale = 1.f / (sqrtf(tot) + 1e-4f);
    u16* orow = outp + (size_t)row * Kp;
    for (int c = threadIdx.x; c < Kp; c += 256)
        orow[c] = f2bf(c < K ? xr[c] * scale : 0.f);
}

// ============ 256x256 GEMM + fused epilogue ============
// MODE 0: v=relu(acc+b);   write C; good_p[plane0] = partial; ss_p = partial
// MODE 1: v=relu(s*acc+b); write C; good_p[plane1] = partial; ss_p = partial
// MODE 2: v=relu(s*acc+b); NO C;    good_p[plane2] = partial
// All partial writes are WRITE-ONLY (no RMW): per-layer planes (L*8+tn),
// reduced across waves in LDS first -> coalesced block writes.

#define AS1G const __attribute__((address_space(1))) void*
#define AS3L __attribute__((address_space(3))) void*

#define STAGE_A(s_, h_) do {                                                     \
    const int sd_ = (s_) & 1; const size_t ko_ = (size_t)(s_) << 6;              \
    _Pragma("unroll") for (int i_ = 0; i_ < 2; ++i_)                             \
        __builtin_amdgcn_global_load_lds(                                        \
            (AS1G)(pA + (size_t)((h_) * 128 + i_ * 64) * K + ko_),               \
            (AS3L)&ldsA[sd_ * 16384 + (h_) * 8192 + i_ * 4096 + w * 512],        \
            16, 0, 0);                                                           \
} while (0)

#define STAGE_B(s_, h_) do {                                                     \
    const int sd_ = (s_) & 1; const size_t ko_ = (size_t)(s_) << 6;              \
    _Pragma("unroll") for (int i_ = 0; i_ < 2; ++i_)                             \
        __builtin_amdgcn_global_load_lds(                                        \
            (AS1G)(pB + (size_t)((h_) * 128 + i_ * 64) * K + ko_),               \
            (AS3L)&ldsB[sd_ * 16384 + (h_) * 8192 + i_ * 4096 + w * 512],        \
            16, 0, 0);                                                           \
} while (0)

#define READ_A(qm_)                                                              \
    _Pragma("unroll") for (int i2_ = 0; i2_ < 4; ++i2_)                          \
    _Pragma("unroll") for (int kk_ = 0; kk_ < 2; ++kk_)                          \
        a_[i2_][kk_] = *(const short8*)&ldsA[d * 16384 + (qm_) * 8192 +          \
            (wr * 64 + i2_ * 16 + rsel) * 64 + ((((kk_ << 2) + hi) ^ lsw) << 3)]

#define READ_B(qn_, bb_)                                                         \
    _Pragma("unroll") for (int j2_ = 0; j2_ < 2; ++j2_)                          \
    _Pragma("unroll") for (int kk_ = 0; kk_ < 2; ++kk_)                          \
        bb_[j2_][kk_] = *(const short8*)&ldsB[d * 16384 + (qn_) * 8192 +         \
            (wc * 32 + j2_ * 16 + rsel) * 64 + ((((kk_ << 2) + hi) ^ lsw) << 3)]

#define MFMA_Q(qm_, qn_, bb_)                                                    \
    _Pragma("unroll") for (int i2_ = 0; i2_ < 4; ++i2_)                          \
    _Pragma("unroll") for (int j2_ = 0; j2_ < 2; ++j2_)                          \
    _Pragma("unroll") for (int kk_ = 0; kk_ < 2; ++kk_)                          \
        acc[(qm_) * 4 + i2_][(qn_) * 2 + j2_] =                                  \
            __builtin_amdgcn_mfma_f32_16x16x32_bf16(                             \
                a_[i2_][kk_], bb_[j2_][kk_],                                     \
                acc[(qm_) * 4 + i2_][(qn_) * 2 + j2_], 0, 0, 0)

#define PH_TAIL(mq_)                                                             \
    asm volatile("s_waitcnt lgkmcnt(0)" ::: "memory");                           \
    __builtin_amdgcn_sched_barrier(0);                                           \
    __builtin_amdgcn_s_setprio(1);                                               \
    mq_;                                                                         \
    __builtin_amdgcn_s_setprio(0);                                               \
    __builtin_amdgcn_s_barrier()

template<int MODE>
__global__ __launch_bounds__(512, 2) void gemm256_fused(
    const u16* __restrict__ A, const u16* __restrict__ W,
    const float* __restrict__ bias, const float* __restrict__ hmat,
    const float* __restrict__ srow, u16* __restrict__ C,
    float* __restrict__ good_p, float* __restrict__ ss_p,
    int N, int K)
{
    __shared__ __align__(16) u16 ldsA[2 * 2 * 128 * 64];  // [dbuf][half][128][64]
    __shared__ __align__(16) u16 ldsB[2 * 2 * 128 * 64];
    __shared__ float s_lds[256];

    const int tid = threadIdx.x;
    const int lane = tid & 63;
    const int w = tid >> 6;               // wave 0..7
    const int wr = w >> 2, wc = w & 3;    // 2M x 4N wave grid
    const int rsel = lane & 15, hi = lane >> 4, lsw = lane & 7;

    // T1: XCD-aware bijective swizzle (grid % 8 == 0)
    int bid = blockIdx.x;
    const int cpx = gridDim.x >> 3;
    bid = (bid & 7) * cpx + (bid >> 3);
    const int ntn = N >> 8;
    const int tm = bid / ntn, tn = bid - tm * ntn;
    const size_t m0 = (size_t)tm << 8, n0 = (size_t)tn << 8;

    const int NS = K >> 6;

    const int srow_t = tid >> 3;
    const int scol = ((tid & 7) ^ (srow_t & 7)) << 3;
    const u16* pA = A + (m0 + srow_t) * (size_t)K + scol;
    const u16* pB = W + (n0 + srow_t) * (size_t)K + scol;

    f32x4 acc[8][4] = {};
    short8 a_[4][2], bA[2][2], bB[2][2];

    if (MODE != 0) { if (tid < 256) s_lds[tid] = srow[m0 + tid]; }

    // prologue: full tile 0, in consumption order; keep Bh1,Ah1 in flight.
    STAGE_A(0, 0); STAGE_B(0, 0); STAGE_B(0, 1); STAGE_A(0, 1);
    asm volatile("s_waitcnt vmcnt(4)" ::: "memory");
    __builtin_amdgcn_s_barrier();
    __builtin_amdgcn_sched_barrier(0);

    for (int s = 0; s < NS; ++s) {
        const int d = s & 1;
        const bool pf = (s + 1 < NS);

        // ---- ph0: quadrant (0,0) ----
        READ_A(0);
        READ_B(0, bA);
        if (pf) {
            STAGE_A(s + 1, 0);
            asm volatile("s_waitcnt vmcnt(4)" ::: "memory");
        } else {
            asm volatile("s_waitcnt vmcnt(2)" ::: "memory");
        }
        __builtin_amdgcn_s_barrier();
        PH_TAIL(MFMA_Q(0, 0, bA));

        // ---- ph1: quadrant (0,1) ----
        READ_B(1, bB);
        if (pf) {
            STAGE_B(s + 1, 0);
            asm volatile("s_waitcnt vmcnt(4)" ::: "memory");
        } else {
            asm volatile("s_waitcnt vmcnt(0)" ::: "memory");
        }
        __builtin_amdgcn_s_barrier();
        PH_TAIL(MFMA_Q(0, 1, bB));

        // ---- ph2: quadrant (1,0) ----
        READ_A(1);
        if (pf) STAGE_B(s + 1, 1);
        __builtin_amdgcn_s_barrier();
        PH_TAIL(MFMA_Q(1, 0, bA));

        // ---- ph3: quadrant (1,1) ----
        if (pf) {
            STAGE_A(s + 1, 1);
            asm volatile("s_waitcnt vmcnt(4)" ::: "memory");
        }
        __builtin_amdgcn_s_barrier();
        __builtin_amdgcn_sched_barrier(0);
        __builtin_amdgcn_s_setprio(1);
        MFMA_Q(1, 1, bB);
        __builtin_amdgcn_s_setprio(0);
        __builtin_amdgcn_s_barrier();
    }

    // ---- epilogue (1): in-place v = relu(s*acc + b) ----
    float bv[4];
#pragma unroll
    for (int j = 0; j < 4; ++j)
        bv[j] = bias[n0 + (j >> 1) * 128 + wc * 32 + (j & 1) * 16 + rsel];
#pragma unroll
    for (int i = 0; i < 8; ++i) {
#pragma unroll
        for (int rg = 0; rg < 4; ++rg) {
            float sv = 1.f;
            if (MODE != 0) sv = s_lds[(i >> 2) * 128 + wr * 64 + (i & 3) * 16 + hi * 4 + rg];
#pragma unroll
            for (int j = 0; j < 4; ++j) {
                float v = acc[i][j][rg] * sv + bv[j];
                acc[i][j][rg] = v > 0.f ? v : 0.f;
            }
        }
    }

    // ---- epilogue (2): goodness + ss, LDS cross-wave reduce, coalesced write ----
    float* red = (float*)ldsA;   // [wc*2+wr][128][11] = 45056 B
    {
        float hreg[10][4];
#pragma unroll
        for (int c = 0; c < 10; ++c)
#pragma unroll
            for (int j = 0; j < 4; ++j)
                hreg[c][j] = hmat[c * 2048 + n0 + (j >> 1) * 128 + wc * 32 + (j & 1) * 16 + rsel];
#pragma unroll
        for (int i = 0; i < 8; ++i) {
#pragma unroll
            for (int rg = 0; rg < 4; ++rg) {
                float p[11];
#pragma unroll
                for (int c = 0; c < 10; ++c) {
                    float a = acc[i][0][rg] * hreg[c][0];
                    a += acc[i][1][rg] * hreg[c][1];
                    a += acc[i][2][rg] * hreg[c][2];
                    a += acc[i][3][rg] * hreg[c][3];
                    p[c] = a;
                }
                p[10] = acc[i][0][rg] * acc[i][0][rg] + acc[i][1][rg] * acc[i][1][rg]
                      + acc[i][2][rg] * acc[i][2][rg] + acc[i][3][rg] * acc[i][3][rg];
#pragma unroll
                for (int m = 1; m < 16; m <<= 1) {
#pragma unroll
                    for (int c = 0; c < 11; ++c) p[c] += __shfl_xor(p[c], m);
                }
                const int lrow = (i >> 2) * 64 + (i & 3) * 16 + hi * 4 + rg;
                if (rsel < 11)
                    red[((wc * 2 + wr) * 128 + lrow) * 11 + rsel] = p[rsel];
            }
        }
    }
    __syncthreads();
    // stage 2: sum 4 wc slices, write per-layer plane (write-only, no RMW)
    for (int idx = tid; idx < 2816; idx += 512) {
        const int c = idx % 11;
        const int r2 = idx / 11;               // 0..255
        const int wrp = r2 >> 7, lrow = r2 & 127;
        float a = red[((0 + wrp) * 128 + lrow) * 11 + c]
                + red[((2 + wrp) * 128 + lrow) * 11 + c]
                + red[((4 + wrp) * 128 + lrow) * 11 + c]
                + red[((6 + wrp) * 128 + lrow) * 11 + c];
        const int grow = (int)m0 + ((lrow >> 6) << 7) + wrp * 64 + (lrow & 63);
        if (c < 10)
            good_p[((size_t)(MODE * 8 + tn) * 16384 + grow) * 10 + c] = a;
        else if (MODE < 2)
            ss_p[(size_t)tn * 16384 + grow] = a;
    }

    // ---- epilogue (3): repack via own 16KB LDS region, coalesced C store ----
    if (MODE < 2) {
        __syncthreads();   // red buffer dead before repack reuses ldsA
        u16* ep = (w < 4) ? &ldsA[w * 8192] : &ldsB[(w - 4) * 8192];
#pragma unroll
        for (int j = 0; j < 4; ++j) {
            const int lc = (j >> 1) * 32 + (j & 1) * 16 + rsel;
            const int slt = lc >> 3, cb = lc & 7;
#pragma unroll
            for (int i = 0; i < 8; ++i) {
                const int lrb = (i >> 2) * 64 + (i & 3) * 16 + hi * 4;
#pragma unroll
                for (int rg = 0; rg < 4; ++rg) {
                    const int lr = lrb + rg;
                    ep[lr * 64 + ((slt ^ (lr & 7)) << 3) + cb] = f2bf(acc[i][j][rg]);
                }
            }
        }
        asm volatile("s_waitcnt lgkmcnt(0)" ::: "memory");
        const int sl = lane & 7;
#pragma unroll
        for (int it2 = 0; it2 < 16; ++it2) {
            const int r = it2 * 8 + (lane >> 3);
            short8 vv = *(const short8*)&ep[r * 64 + ((sl ^ (r & 7)) << 3)];
            const size_t gr = m0 + (size_t)((r >> 6) * 128 + wr * 64 + (r & 63));
            const size_t gc = n0 + (size_t)((sl >> 2) * 128 + wc * 32 + (sl & 3) * 8);
            *(short8*)&C[gr * (size_t)N + gc] = vv;
        }
    }
}

// ---------------- s[r] = 1/(sqrt(sum_tn ss_p)+eps) ----------------
__global__ __launch_bounds__(256) void reduce_s_kernel(
    const float* __restrict__ ss_p, float* __restrict__ s)
{
    const int r = blockIdx.x * 256 + threadIdx.x;
    float a = 0.f;
#pragma unroll
    for (int slot = 0; slot < 8; ++slot) a += ss_p[(size_t)slot * 16384 + r];
    s[r] = 1.f / (sqrtf(a) + 1e-4f);
}

// ---------------- argmax over 24 summed class planes ----------------
__global__ __launch_bounds__(256) void argmax_kernel(
    const float* __restrict__ good_p, int* __restrict__ outp)
{
    const int r = blockIdx.x * 256 + threadIdx.x;
    float cls[10];
#pragma unroll
    for (int c = 0; c < 10; ++c) cls[c] = 0.f;
    for (int pl = 0; pl < 24; ++pl) {
        const float* tp = good_p + ((size_t)pl * 16384 + r) * 10;
#pragma unroll
        for (int c = 0; c < 10; ++c) cls[c] += tp[c];
    }
    float best = -3.4e38f;
    int bi = 0;
#pragma unroll
    for (int c = 0; c < 10; ++c) {
        if (cls[c] > best) { best = cls[c]; bi = c; }  // strict > : ties -> lowest
    }
    outp[r] = bi;
}

extern "C" void kernel_launch(void* const* d_in, const int* in_sizes, int n_in,
                              void* d_out, int out_size, void* d_ws, size_t ws_size,
                              hipStream_t stream)
{
    const float* x  = (const float*)d_in[0];
    const float* W0 = (const float*)d_in[1];
    const float* b0 = (const float*)d_in[2];
    const float* h0 = (const float*)d_in[3];
    const float* W1 = (const float*)d_in[4];
    const float* b1 = (const float*)d_in[5];
    const float* h1 = (const float*)d_in[6];
    const float* W2 = (const float*)d_in[7];
    const float* b2 = (const float*)d_in[8];
    const float* h2 = (const float*)d_in[9];
    int* out = (int*)d_out;

    const int M = 16384, N = 2048, K0 = 784, Kp0 = 896, D = 2048;

    char* ws = (char*)d_ws;
    size_t off = 0;
    auto alloc = [&](size_t bytes) -> void* {
        void* p = ws + off;
        off += (bytes + 255) & ~(size_t)255;
        return p;
    };
    u16* buf1  = (u16*)alloc((size_t)M * D * 2);     // x1 (layer-0 output)
    u16* buf2  = (u16*)alloc((size_t)M * D * 2);     // A0p, then x2
    u16* W0p   = (u16*)alloc((size_t)N * Kp0 * 2);
    u16* W1b   = (u16*)alloc((size_t)N * D * 2);
    u16* W2b   = (u16*)alloc((size_t)N * D * 2);
    float* good_p = (float*)alloc((size_t)24 * M * 10 * 4);  // 15.7 MB, write-once
    float* ss_p   = (float*)alloc((size_t)8 * M * 4);        // 512 KB
    float* svec   = (float*)alloc((size_t)M * 4);
    u16* A0p = buf2;  // 896-stride rows fit inside 2048-stride buffer

    convert_w_kernel<<<2048, 256, 0, stream>>>(W0, W0p, K0, Kp0, (long)N * Kp0);
    convert_w_kernel<<<2048, 256, 0, stream>>>(W1, W1b, D, D, (long)N * D);
    convert_w_kernel<<<2048, 256, 0, stream>>>(W2, W2b, D, D, (long)N * D);

    norm_x0_kernel<<<M, 256, 0, stream>>>(x, A0p, K0, Kp0);

    const int g256 = (M / 256) * (N / 256);  // 512 blocks, %8 == 0
    gemm256_fused<0><<<g256, 512, 0, stream>>>(A0p, W0p, b0, h0, nullptr, buf1,
                                               good_p, ss_p, N, Kp0);
    reduce_s_kernel<<<M / 256, 256, 0, stream>>>(ss_p, svec);
    gemm256_fused<1><<<g256, 512, 0, stream>>>(buf1, W1b, b1, h1, svec, buf2,
                                               good_p, ss_p, N, D);
    reduce_s_kernel<<<M / 256, 256, 0, stream>>>(ss_p, svec);
    gemm256_fused<2><<<g256, 512, 0, stream>>>(buf2, W2b, b2, h2, svec, nullptr,
                                               good_p, nullptr, N, D);
    argmax_kernel<<<M / 256, 256, 0, stream>>>(good_p, out);
}

// Round 12
// 498.557 us; speedup vs baseline: 1.6413x; 1.3528x over previous
//
#include <hip/hip_runtime.h>

typedef __attribute__((ext_vector_type(8))) short short8;
typedef __attribute__((ext_vector_type(4))) float f32x4;
typedef unsigned short u16;

#define DEVI static __device__ __forceinline__

DEVI float bf2f(u16 u) {
    unsigned int x = ((unsigned int)u) << 16;
    float f;
    __builtin_memcpy(&f, &x, 4);
    return f;
}
DEVI u16 f2bf(float f) {
    unsigned int x;
    __builtin_memcpy(&x, &f, 4);
    unsigned int r = x + 0x7fffu + ((x >> 16) & 1u);
    return (u16)(r >> 16);
}

// ---------------- W f32 -> bf16 (with K padding to Kp) ----------------
__global__ __launch_bounds__(256) void convert_w_kernel(
    const float* __restrict__ wsrc, u16* __restrict__ wdst,
    int K, int Kp, long total_elems)
{
    long idx = (long)blockIdx.x * 256 + threadIdx.x;
    const long stride = (long)gridDim.x * 256;
    for (; idx < total_elems; idx += stride) {
        long rw = idx / Kp;
        int col = (int)(idx - rw * Kp);
        float v = (col < K) ? wsrc[rw * K + col] : 0.f;
        wdst[idx] = f2bf(v);
    }
}

// ------- row L2-normalize x0 (f32, K cols) -> bf16 (Kp cols, zero pad) -------
__global__ __launch_bounds__(256) void norm_x0_kernel(
    const float* __restrict__ x, u16* __restrict__ outp, int K, int Kp)
{
    const int row = blockIdx.x;
    const float* xr = x + (size_t)row * K;
    float ss = 0.f;
    for (int c = threadIdx.x; c < K; c += 256) { float v = xr[c]; ss += v * v; }
#pragma unroll
    for (int off = 32; off; off >>= 1) ss += __shfl_xor(ss, off);
    __shared__ float red[4];
    if ((threadIdx.x & 63) == 0) red[threadIdx.x >> 6] = ss;
    __syncthreads();
    const float tot = red[0] + red[1] + red[2] + red[3];
    const float scale = 1.f / (sqrtf(tot) + 1e-4f);
    u16* orow = outp + (size_t)row * Kp;
    for (int c = threadIdx.x; c < Kp; c += 256)
        orow[c] = f2bf(c < K ? xr[c] * scale : 0.f);
}

// ============ 256x256 GEMM + fused MFMA epilogue ============
// MODE 0: v=relu(acc+b);   write C; good_p[plane0] = partial; ss_p = partial
// MODE 1: v=relu(s*acc+b); write C; good_p[plane1] = partial; ss_p = partial
// MODE 2: v=relu(s*acc+b); NO C;    good_p[plane2] = partial
// Goodness/ss computed by MFMA over the repacked LDS v-tile (no shfl storm).
// Partial writes are WRITE-ONLY planes (no RMW), cross-wave reduced in LDS.

#define AS1G const __attribute__((address_space(1))) void*
#define AS3L __attribute__((address_space(3))) void*

#define STAGE_A(s_, h_) do {                                                     \
    const int sd_ = (s_) & 1; const size_t ko_ = (size_t)(s_) << 6;              \
    _Pragma("unroll") for (int i_ = 0; i_ < 2; ++i_)                             \
        __builtin_amdgcn_global_load_lds(                                        \
            (AS1G)(pA + (size_t)((h_) * 128 + i_ * 64) * K + ko_),               \
            (AS3L)&ldsA[sd_ * 16384 + (h_) * 8192 + i_ * 4096 + w * 512],        \
            16, 0, 0);                                                           \
} while (0)

#define STAGE_B(s_, h_) do {                                                     \
    const int sd_ = (s_) & 1; const size_t ko_ = (size_t)(s_) << 6;              \
    _Pragma("unroll") for (int i_ = 0; i_ < 2; ++i_)                             \
        __builtin_amdgcn_global_load_lds(                                        \
            (AS1G)(pB + (size_t)((h_) * 128 + i_ * 64) * K + ko_),               \
            (AS3L)&ldsB[sd_ * 16384 + (h_) * 8192 + i_ * 4096 + w * 512],        \
            16, 0, 0);                                                           \
} while (0)

#define READ_A(qm_)                                                              \
    _Pragma("unroll") for (int i2_ = 0; i2_ < 4; ++i2_)                          \
    _Pragma("unroll") for (int kk_ = 0; kk_ < 2; ++kk_)                          \
        a_[i2_][kk_] = *(const short8*)&ldsA[d * 16384 + (qm_) * 8192 +          \
            (wr * 64 + i2_ * 16 + rsel) * 64 + ((((kk_ << 2) + hi) ^ lsw) << 3)]

#define READ_B(qn_, bb_)                                                         \
    _Pragma("unroll") for (int j2_ = 0; j2_ < 2; ++j2_)                          \
    _Pragma("unroll") for (int kk_ = 0; kk_ < 2; ++kk_)                          \
        bb_[j2_][kk_] = *(const short8*)&ldsB[d * 16384 + (qn_) * 8192 +         \
            (wc * 32 + j2_ * 16 + rsel) * 64 + ((((kk_ << 2) + hi) ^ lsw) << 3)]

#define MFMA_Q(qm_, qn_, bb_)                                                    \
    _Pragma("unroll") for (int i2_ = 0; i2_ < 4; ++i2_)                          \
    _Pragma("unroll") for (int j2_ = 0; j2_ < 2; ++j2_)                          \
    _Pragma("unroll") for (int kk_ = 0; kk_ < 2; ++kk_)                          \
        acc[(qm_) * 4 + i2_][(qn_) * 2 + j2_] =                                  \
            __builtin_amdgcn_mfma_f32_16x16x32_bf16(                             \
                a_[i2_][kk_], bb_[j2_][kk_],                                     \
                acc[(qm_) * 4 + i2_][(qn_) * 2 + j2_], 0, 0, 0)

#define PH_TAIL(mq_)                                                             \
    asm volatile("s_waitcnt lgkmcnt(0)" ::: "memory");                           \
    __builtin_amdgcn_sched_barrier(0);                                           \
    __builtin_amdgcn_s_setprio(1);                                               \
    mq_;                                                                         \
    __builtin_amdgcn_s_setprio(0);                                               \
    __builtin_amdgcn_s_barrier()

template<int MODE>
__global__ __launch_bounds__(512, 2) void gemm256_fused(
    const u16* __restrict__ A, const u16* __restrict__ W,
    const float* __restrict__ bias, const float* __restrict__ hmat,
    const float* __restrict__ srow, u16* __restrict__ C,
    float* __restrict__ good_p, float* __restrict__ ss_p,
    int N, int K)
{
    __shared__ __align__(16) u16 ldsA[2 * 2 * 128 * 64];  // [dbuf][half][128][64]
    __shared__ __align__(16) u16 ldsB[2 * 2 * 128 * 64];
    __shared__ float s_lds[256];

    const int tid = threadIdx.x;
    const int lane = tid & 63;
    const int w = tid >> 6;               // wave 0..7
    const int wr = w >> 2, wc = w & 3;    // 2M x 4N wave grid
    const int rsel = lane & 15, hi = lane >> 4, lsw = lane & 7;

    // T1: XCD-aware bijective swizzle (grid % 8 == 0)
    int bid = blockIdx.x;
    const int cpx = gridDim.x >> 3;
    bid = (bid & 7) * cpx + (bid >> 3);
    const int ntn = N >> 8;
    const int tm = bid / ntn, tn = bid - tm * ntn;
    const size_t m0 = (size_t)tm << 8, n0 = (size_t)tn << 8;

    const int NS = K >> 6;

    const int srow_t = tid >> 3;
    const int scol = ((tid & 7) ^ (srow_t & 7)) << 3;
    const u16* pA = A + (m0 + srow_t) * (size_t)K + scol;
    const u16* pB = W + (n0 + srow_t) * (size_t)K + scol;

    f32x4 acc[8][4] = {};
    short8 a_[4][2], bA[2][2], bB[2][2];

    if (MODE != 0) { if (tid < 256) s_lds[tid] = srow[m0 + tid]; }

    // prologue: full tile 0, in consumption order; keep Bh1,Ah1 in flight.
    STAGE_A(0, 0); STAGE_B(0, 0); STAGE_B(0, 1); STAGE_A(0, 1);
    asm volatile("s_waitcnt vmcnt(4)" ::: "memory");
    __builtin_amdgcn_s_barrier();
    __builtin_amdgcn_sched_barrier(0);

    for (int s = 0; s < NS; ++s) {
        const int d = s & 1;
        const bool pf = (s + 1 < NS);

        // ---- ph0: quadrant (0,0) ----
        READ_A(0);
        READ_B(0, bA);
        if (pf) {
            STAGE_A(s + 1, 0);
            asm volatile("s_waitcnt vmcnt(4)" ::: "memory");
        } else {
            asm volatile("s_waitcnt vmcnt(2)" ::: "memory");
        }
        __builtin_amdgcn_s_barrier();
        PH_TAIL(MFMA_Q(0, 0, bA));

        // ---- ph1: quadrant (0,1) ----
        READ_B(1, bB);
        if (pf) {
            STAGE_B(s + 1, 0);
            asm volatile("s_waitcnt vmcnt(4)" ::: "memory");
        } else {
            asm volatile("s_waitcnt vmcnt(0)" ::: "memory");
        }
        __builtin_amdgcn_s_barrier();
        PH_TAIL(MFMA_Q(0, 1, bB));

        // ---- ph2: quadrant (1,0) ----
        READ_A(1);
        if (pf) STAGE_B(s + 1, 1);
        __builtin_amdgcn_s_barrier();
        PH_TAIL(MFMA_Q(1, 0, bA));

        // ---- ph3: quadrant (1,1) ----
        if (pf) {
            STAGE_A(s + 1, 1);
            asm volatile("s_waitcnt vmcnt(4)" ::: "memory");
        }
        __builtin_amdgcn_s_barrier();
        __builtin_amdgcn_sched_barrier(0);
        __builtin_amdgcn_s_setprio(1);
        MFMA_Q(1, 1, bB);
        __builtin_amdgcn_s_setprio(0);
        __builtin_amdgcn_s_barrier();
    }

    // ---- epilogue (1): in-place v = relu(s*acc + b) ----
    float bv[4];
#pragma unroll
    for (int j = 0; j < 4; ++j)
        bv[j] = bias[n0 + (j >> 1) * 128 + wc * 32 + (j & 1) * 16 + rsel];
#pragma unroll
    for (int i = 0; i < 8; ++i) {
#pragma unroll
        for (int rg = 0; rg < 4; ++rg) {
            float sv = 1.f;
            if (MODE != 0) sv = s_lds[(i >> 2) * 128 + wr * 64 + (i & 3) * 16 + hi * 4 + rg];
#pragma unroll
            for (int j = 0; j < 4; ++j) {
                float v = acc[i][j][rg] * sv + bv[j];
                acc[i][j][rg] = v > 0.f ? v : 0.f;
            }
        }
    }

    // ---- epilogue (2): repack v (bf16) into own 16KB LDS region (all modes) ----
    u16* ep = (w < 4) ? &ldsA[w * 8192] : &ldsB[(w - 4) * 8192];
#pragma unroll
    for (int j = 0; j < 4; ++j) {
        const int lc = (j >> 1) * 32 + (j & 1) * 16 + rsel;
        const int slt = lc >> 3, cb = lc & 7;
#pragma unroll
        for (int i = 0; i < 8; ++i) {
            const int lrb = (i >> 2) * 64 + (i & 3) * 16 + hi * 4;
#pragma unroll
            for (int rg = 0; rg < 4; ++rg) {
                const int lr = lrb + rg;
                ep[lr * 64 + ((slt ^ (lr & 7)) << 3) + cb] = f2bf(acc[i][j][rg]);
            }
        }
    }
    asm volatile("s_waitcnt lgkmcnt(0)" ::: "memory");  // own region only

    // ---- epilogue (3): coalesced C store (MODE<2) ----
    if (MODE < 2) {
        const int sl = lane & 7;
#pragma unroll
        for (int it2 = 0; it2 < 16; ++it2) {
            const int r = it2 * 8 + (lane >> 3);
            short8 vv = *(const short8*)&ep[r * 64 + ((sl ^ (r & 7)) << 3)];
            const size_t gr = m0 + (size_t)((r >> 6) * 128 + wr * 64 + (r & 63));
            const size_t gc = n0 + (size_t)((sl >> 2) * 128 + wc * 32 + (sl & 3) * 8);
            *(short8*)&C[gr * (size_t)N + gc] = vv;
        }
    }

    // ---- epilogue (4): goodness (+ss) via MFMA on the ep tile ----
    // B-frag from h: lane class = rsel (<10, else 0); k elem = hi*8+e;
    // local col lc = ks*32 + hi*8 + e -> global col n0 + ks*128 + wc*32 + hi*8 + e.
    short8 hfr[2];
#pragma unroll
    for (int ks = 0; ks < 2; ++ks) {
#pragma unroll
        for (int e = 0; e < 8; ++e) {
            const int gc = (int)n0 + ks * 128 + wc * 32 + hi * 8 + e;
            const float hv = (rsel < 10) ? hmat[rsel * 2048 + gc] : 0.f;
            hfr[ks][e] = (short)f2bf(hv);
        }
    }
    f32x4 gacc[8], ssacc[8];
#pragma unroll
    for (int rt = 0; rt < 8; ++rt) { gacc[rt] = (f32x4){0,0,0,0}; ssacc[rt] = (f32x4){0,0,0,0}; }
#pragma unroll
    for (int rt = 0; rt < 8; ++rt) {
#pragma unroll
        for (int ks = 0; ks < 2; ++ks) {
            short8 a2 = *(const short8*)&ep[(rt * 16 + rsel) * 64 + ((((ks << 2) + hi) ^ lsw) << 3)];
            gacc[rt] = __builtin_amdgcn_mfma_f32_16x16x32_bf16(a2, hfr[ks], gacc[rt], 0, 0, 0);
            if (MODE < 2)
                ssacc[rt] = __builtin_amdgcn_mfma_f32_16x16x32_bf16(a2, a2, ssacc[rt], 0, 0, 0);
        }
    }
    __syncthreads();   // all ep reads (C store + MFMA) complete before red overlays ldsA

    // ---- epilogue (5): cross-wave reduce in LDS, write-only global partials ----
    float* red = (float*)ldsA;   // [8 slices][128 rows][11] = 45056 B
    const int slice = wc * 2 + wr;
#pragma unroll
    for (int rt = 0; rt < 8; ++rt) {
        if (rsel < 10) {
#pragma unroll
            for (int rg = 0; rg < 4; ++rg)
                red[(slice * 128 + rt * 16 + hi * 4 + rg) * 11 + rsel] = gacc[rt][rg];
        }
        if (MODE < 2) {
            if ((rsel >> 2) == hi)
                red[(slice * 128 + rt * 16 + rsel) * 11 + 10] = ssacc[rt][rsel & 3];
        }
    }
    __syncthreads();
    for (int idx = tid; idx < 2816; idx += 512) {
        const int c = idx % 11;
        const int r2 = idx / 11;               // 0..255
        const int wrp = r2 >> 7, lrow = r2 & 127;
        float a = red[((0 + wrp) * 128 + lrow) * 11 + c]
                + red[((2 + wrp) * 128 + lrow) * 11 + c]
                + red[((4 + wrp) * 128 + lrow) * 11 + c]
                + red[((6 + wrp) * 128 + lrow) * 11 + c];
        const int grow = (int)m0 + ((lrow >> 6) << 7) + wrp * 64 + (lrow & 63);
        if (c < 10)
            good_p[((size_t)(MODE * 8 + tn) * 16384 + grow) * 10 + c] = a;
        else if (MODE < 2)
            ss_p[(size_t)tn * 16384 + grow] = a;
    }
}

// ---------------- s[r] = 1/(sqrt(sum_tn ss_p)+eps) ----------------
__global__ __launch_bounds__(256) void reduce_s_kernel(
    const float* __restrict__ ss_p, float* __restrict__ s)
{
    const int r = blockIdx.x * 256 + threadIdx.x;
    float a = 0.f;
#pragma unroll
    for (int slot = 0; slot < 8; ++slot) a += ss_p[(size_t)slot * 16384 + r];
    s[r] = 1.f / (sqrtf(a) + 1e-4f);
}

// ---------------- argmax over 24 summed class planes ----------------
__global__ __launch_bounds__(256) void argmax_kernel(
    const float* __restrict__ good_p, int* __restrict__ outp)
{
    const int r = blockIdx.x * 256 + threadIdx.x;
    float cls[10];
#pragma unroll
    for (int c = 0; c < 10; ++c) cls[c] = 0.f;
    for (int pl = 0; pl < 24; ++pl) {
        const float* tp = good_p + ((size_t)pl * 16384 + r) * 10;
#pragma unroll
        for (int c = 0; c < 10; ++c) cls[c] += tp[c];
    }
    float best = -3.4e38f;
    int bi = 0;
#pragma unroll
    for (int c = 0; c < 10; ++c) {
        if (cls[c] > best) { best = cls[c]; bi = c; }  // strict > : ties -> lowest
    }
    outp[r] = bi;
}

extern "C" void kernel_launch(void* const* d_in, const int* in_sizes, int n_in,
                              void* d_out, int out_size, void* d_ws, size_t ws_size,
                              hipStream_t stream)
{
    const float* x  = (const float*)d_in[0];
    const float* W0 = (const float*)d_in[1];
    const float* b0 = (const float*)d_in[2];
    const float* h0 = (const float*)d_in[3];
    const float* W1 = (const float*)d_in[4];
    const float* b1 = (const float*)d_in[5];
    const float* h1 = (const float*)d_in[6];
    const float* W2 = (const float*)d_in[7];
    const float* b2 = (const float*)d_in[8];
    const float* h2 = (const float*)d_in[9];
    int* out = (int*)d_out;

    const int M = 16384, N = 2048, K0 = 784, Kp0 = 896, D = 2048;

    char* ws = (char*)d_ws;
    size_t off = 0;
    auto alloc = [&](size_t bytes) -> void* {
        void* p = ws + off;
        off += (bytes + 255) & ~(size_t)255;
        return p;
    };
    u16* buf1  = (u16*)alloc((size_t)M * D * 2);     // x1 (layer-0 output)
    u16* buf2  = (u16*)alloc((size_t)M * D * 2);     // A0p, then x2
    u16* W0p   = (u16*)alloc((size_t)N * Kp0 * 2);
    u16* W1b   = (u16*)alloc((size_t)N * D * 2);
    u16* W2b   = (u16*)alloc((size_t)N * D * 2);
    float* good_p = (float*)alloc((size_t)24 * M * 10 * 4);  // 15.7 MB, write-once
    float* ss_p   = (float*)alloc((size_t)8 * M * 4);        // 512 KB
    float* svec   = (float*)alloc((size_t)M * 4);
    u16* A0p = buf2;  // 896-stride rows fit inside 2048-stride buffer

    convert_w_kernel<<<2048, 256, 0, stream>>>(W0, W0p, K0, Kp0, (long)N * Kp0);
    convert_w_kernel<<<2048, 256, 0, stream>>>(W1, W1b, D, D, (long)N * D);
    convert_w_kernel<<<2048, 256, 0, stream>>>(W2, W2b, D, D, (long)N * D);

    norm_x0_kernel<<<M, 256, 0, stream>>>(x, A0p, K0, Kp0);

    const int g256 = (M / 256) * (N / 256);  // 512 blocks, %8 == 0
    gemm256_fused<0><<<g256, 512, 0, stream>>>(A0p, W0p, b0, h0, nullptr, buf1,
                                               good_p, ss_p, N, Kp0);
    reduce_s_kernel<<<M / 256, 256, 0, stream>>>(ss_p, svec);
    gemm256_fused<1><<<g256, 512, 0, stream>>>(buf1, W1b, b1, h1, svec, buf2,
                                               good_p, ss_p, N, D);
    reduce_s_kernel<<<M / 256, 256, 0, stream>>>(ss_p, svec);
    gemm256_fused<2><<<g256, 512, 0, stream>>>(buf2, W2b, b2, h2, svec, nullptr,
                                               good_p, nullptr, N, D);
    argmax_kernel<<<M / 256, 256, 0, stream>>>(good_p, out);
}

// Round 13
// 486.260 us; speedup vs baseline: 1.6829x; 1.0253x over previous
//
#include <hip/hip_runtime.h>

typedef __attribute__((ext_vector_type(8))) short short8;
typedef __attribute__((ext_vector_type(4))) float f32x4;
typedef unsigned short u16;

#define DEVI static __device__ __forceinline__

DEVI float bf2f(u16 u) {
    unsigned int x = ((unsigned int)u) << 16;
    float f;
    __builtin_memcpy(&f, &x, 4);
    return f;
}
DEVI u16 f2bf(float f) {
    unsigned int x;
    __builtin_memcpy(&x, &f, 4);
    unsigned int r = x + 0x7fffu + ((x >> 16) & 1u);
    return (u16)(r >> 16);
}

// ---------------- W f32 -> bf16 (with K padding to Kp) ----------------
__global__ __launch_bounds__(256) void convert_w_kernel(
    const float* __restrict__ wsrc, u16* __restrict__ wdst,
    int K, int Kp, long total_elems)
{
    long idx = (long)blockIdx.x * 256 + threadIdx.x;
    const long stride = (long)gridDim.x * 256;
    for (; idx < total_elems; idx += stride) {
        long rw = idx / Kp;
        int col = (int)(idx - rw * Kp);
        float v = (col < K) ? wsrc[rw * K + col] : 0.f;
        wdst[idx] = f2bf(v);
    }
}

// ------- row L2-normalize x0 (f32, K cols) -> bf16 (Kp cols, zero pad) -------
__global__ __launch_bounds__(256) void norm_x0_kernel(
    const float* __restrict__ x, u16* __restrict__ outp, int K, int Kp)
{
    const int row = blockIdx.x;
    const float* xr = x + (size_t)row * K;
    float ss = 0.f;
    for (int c = threadIdx.x; c < K; c += 256) { float v = xr[c]; ss += v * v; }
#pragma unroll
    for (int off = 32; off; off >>= 1) ss += __shfl_xor(ss, off);
    __shared__ float red[4];
    if ((threadIdx.x & 63) == 0) red[threadIdx.x >> 6] = ss;
    __syncthreads();
    const float tot = red[0] + red[1] + red[2] + red[3];
    const float scale = 1.f / (sqrtf(tot) + 1e-4f);
    u16* orow = outp + (size_t)row * Kp;
    for (int c = threadIdx.x; c < Kp; c += 256)
        orow[c] = f2bf(c < K ? xr[c] * scale : 0.f);
}

// ============ 256x256 GEMM + fused MFMA epilogue ============
// MODE 0: v=relu(acc+b);   write C; good_p[plane0] = partial; ss_p = partial
// MODE 1: v=relu(s*acc+b); write C; good_p[plane1] = partial; ss_p = partial
// MODE 2: v=relu(s*acc+b); NO C;    good_p[plane2] = partial
// Loop: 4 phases/K-tile, ONE barrier per phase (post-MFMA barrier doubles as
// the collective vmcnt rendezvous), 2 counted vmcnt(4)/K-tile (ph0 drains
// G(s-1,1)={Bh1,Ah1}(s); ph3 drains G(s,0)={Ah0,Bh0}(s+1)); all staged
// half-tiles get 3 phases of HBM lead. Stages target buf d^1 only (WAR-safe:
// its readers lgkm-drained >=4 phases prior). lgkm0+sched_barrier before each
// MFMA cluster (rule #18).

#define AS1G const __attribute__((address_space(1))) void*
#define AS3L __attribute__((address_space(3))) void*

#define STAGE_A(s_, h_) do {                                                     \
    const int sd_ = (s_) & 1; const size_t ko_ = (size_t)(s_) << 6;              \
    _Pragma("unroll") for (int i_ = 0; i_ < 2; ++i_)                             \
        __builtin_amdgcn_global_load_lds(                                        \
            (AS1G)(pA + (size_t)((h_) * 128 + i_ * 64) * K + ko_),               \
            (AS3L)&ldsA[sd_ * 16384 + (h_) * 8192 + i_ * 4096 + w * 512],        \
            16, 0, 0);                                                           \
} while (0)

#define STAGE_B(s_, h_) do {                                                     \
    const int sd_ = (s_) & 1; const size_t ko_ = (size_t)(s_) << 6;              \
    _Pragma("unroll") for (int i_ = 0; i_ < 2; ++i_)                             \
        __builtin_amdgcn_global_load_lds(                                        \
            (AS1G)(pB + (size_t)((h_) * 128 + i_ * 64) * K + ko_),               \
            (AS3L)&ldsB[sd_ * 16384 + (h_) * 8192 + i_ * 4096 + w * 512],        \
            16, 0, 0);                                                           \
} while (0)

#define READ_A(qm_)                                                              \
    _Pragma("unroll") for (int i2_ = 0; i2_ < 4; ++i2_)                          \
    _Pragma("unroll") for (int kk_ = 0; kk_ < 2; ++kk_)                          \
        a_[i2_][kk_] = *(const short8*)&ldsA[d * 16384 + (qm_) * 8192 +          \
            (wr * 64 + i2_ * 16 + rsel) * 64 + ((((kk_ << 2) + hi) ^ lsw) << 3)]

#define READ_B(qn_, bb_)                                                         \
    _Pragma("unroll") for (int j2_ = 0; j2_ < 2; ++j2_)                          \
    _Pragma("unroll") for (int kk_ = 0; kk_ < 2; ++kk_)                          \
        bb_[j2_][kk_] = *(const short8*)&ldsB[d * 16384 + (qn_) * 8192 +         \
            (wc * 32 + j2_ * 16 + rsel) * 64 + ((((kk_ << 2) + hi) ^ lsw) << 3)]

#define MFMA_Q(qm_, qn_, bb_)                                                    \
    _Pragma("unroll") for (int i2_ = 0; i2_ < 4; ++i2_)                          \
    _Pragma("unroll") for (int j2_ = 0; j2_ < 2; ++j2_)                          \
    _Pragma("unroll") for (int kk_ = 0; kk_ < 2; ++kk_)                          \
        acc[(qm_) * 4 + i2_][(qn_) * 2 + j2_] =                                  \
            __builtin_amdgcn_mfma_f32_16x16x32_bf16(                             \
                a_[i2_][kk_], bb_[j2_][kk_],                                     \
                acc[(qm_) * 4 + i2_][(qn_) * 2 + j2_], 0, 0, 0)

#define MFMA_TAIL(mq_)                                                           \
    asm volatile("s_waitcnt lgkmcnt(0)" ::: "memory");                           \
    __builtin_amdgcn_sched_barrier(0);                                           \
    __builtin_amdgcn_s_setprio(1);                                               \
    mq_;                                                                         \
    __builtin_amdgcn_s_setprio(0);                                               \
    __builtin_amdgcn_s_barrier()

template<int MODE>
__global__ __launch_bounds__(512, 2) void gemm256_fused(
    const u16* __restrict__ A, const u16* __restrict__ W,
    const float* __restrict__ bias, const float* __restrict__ hmat,
    const float* __restrict__ srow, u16* __restrict__ C,
    float* __restrict__ good_p, float* __restrict__ ss_p,
    int N, int K)
{
    __shared__ __align__(16) u16 ldsA[2 * 2 * 128 * 64];  // [dbuf][half][128][64]
    __shared__ __align__(16) u16 ldsB[2 * 2 * 128 * 64];
    __shared__ float s_lds[256];

    const int tid = threadIdx.x;
    const int lane = tid & 63;
    const int w = tid >> 6;               // wave 0..7
    const int wr = w >> 2, wc = w & 3;    // 2M x 4N wave grid
    const int rsel = lane & 15, hi = lane >> 4, lsw = lane & 7;

    // T1: XCD-aware bijective swizzle (grid % 8 == 0)
    int bid = blockIdx.x;
    const int cpx = gridDim.x >> 3;
    bid = (bid & 7) * cpx + (bid >> 3);
    const int ntn = N >> 8;
    const int tm = bid / ntn, tn = bid - tm * ntn;
    const size_t m0 = (size_t)tm << 8, n0 = (size_t)tn << 8;

    const int NS = K >> 6;

    const int srow_t = tid >> 3;
    const int scol = ((tid & 7) ^ (srow_t & 7)) << 3;
    const u16* pA = A + (m0 + srow_t) * (size_t)K + scol;
    const u16* pB = W + (n0 + srow_t) * (size_t)K + scol;

    f32x4 acc[8][4] = {};
    short8 a_[4][2], bA[2][2], bB[2][2];

    if (MODE != 0) { if (tid < 256) s_lds[tid] = srow[m0 + tid]; }

    // prologue: full tile 0 in consumption order; keep Bh1,Ah1 in flight.
    STAGE_A(0, 0); STAGE_B(0, 0); STAGE_B(0, 1); STAGE_A(0, 1);
    asm volatile("s_waitcnt vmcnt(4)" ::: "memory");
    __builtin_amdgcn_s_barrier();
    __builtin_amdgcn_sched_barrier(0);

    for (int s = 0; s < NS; ++s) {
        const int d = s & 1;
        const bool pf = (s + 1 < NS);

        // ---- ph0: q(0,0); stage G(s+1,0)={Ah0,Bh0}; drain G(s-1,1) ----
        READ_A(0);
        READ_B(0, bA);
        if (pf) {
            STAGE_A(s + 1, 0);
            STAGE_B(s + 1, 0);
            asm volatile("s_waitcnt vmcnt(4)" ::: "memory");
        } else {
            asm volatile("s_waitcnt vmcnt(0)" ::: "memory");
        }
        MFMA_TAIL(MFMA_Q(0, 0, bA));

        // ---- ph1: q(0,1); stage G(s+1,1)={Bh1,Ah1} ----
        READ_B(1, bB);
        if (pf) { STAGE_B(s + 1, 1); STAGE_A(s + 1, 1); }
        MFMA_TAIL(MFMA_Q(0, 1, bB));

        // ---- ph2: q(1,0) ----
        READ_A(1);
        MFMA_TAIL(MFMA_Q(1, 0, bA));

        // ---- ph3: q(1,1); drain G(s,0) for next ph0 ----
        if (pf) asm volatile("s_waitcnt vmcnt(4)" ::: "memory");
        __builtin_amdgcn_sched_barrier(0);
        __builtin_amdgcn_s_setprio(1);
        MFMA_Q(1, 1, bB);
        __builtin_amdgcn_s_setprio(0);
        __builtin_amdgcn_s_barrier();
    }

    // ---- epilogue (1): in-place v = relu(s*acc + b) ----
    float bv[4];
#pragma unroll
    for (int j = 0; j < 4; ++j)
        bv[j] = bias[n0 + (j >> 1) * 128 + wc * 32 + (j & 1) * 16 + rsel];
#pragma unroll
    for (int i = 0; i < 8; ++i) {
#pragma unroll
        for (int rg = 0; rg < 4; ++rg) {
            float sv = 1.f;
            if (MODE != 0) sv = s_lds[(i >> 2) * 128 + wr * 64 + (i & 3) * 16 + hi * 4 + rg];
#pragma unroll
            for (int j = 0; j < 4; ++j) {
                float v = acc[i][j][rg] * sv + bv[j];
                acc[i][j][rg] = v > 0.f ? v : 0.f;
            }
        }
    }

    // ---- epilogue (2): repack v (bf16) into own 16KB LDS region (all modes) ----
    u16* ep = (w < 4) ? &ldsA[w * 8192] : &ldsB[(w - 4) * 8192];
#pragma unroll
    for (int j = 0; j < 4; ++j) {
        const int lc = (j >> 1) * 32 + (j & 1) * 16 + rsel;
        const int slt = lc >> 3, cb = lc & 7;
#pragma unroll
        for (int i = 0; i < 8; ++i) {
            const int lrb = (i >> 2) * 64 + (i & 3) * 16 + hi * 4;
#pragma unroll
            for (int rg = 0; rg < 4; ++rg) {
                const int lr = lrb + rg;
                ep[lr * 64 + ((slt ^ (lr & 7)) << 3) + cb] = f2bf(acc[i][j][rg]);
            }
        }
    }
    asm volatile("s_waitcnt lgkmcnt(0)" ::: "memory");  // own region only

    // ---- epilogue (3): coalesced C store (MODE<2) ----
    if (MODE < 2) {
        const int sl = lane & 7;
#pragma unroll
        for (int it2 = 0; it2 < 16; ++it2) {
            const int r = it2 * 8 + (lane >> 3);
            short8 vv = *(const short8*)&ep[r * 64 + ((sl ^ (r & 7)) << 3)];
            const size_t gr = m0 + (size_t)((r >> 6) * 128 + wr * 64 + (r & 63));
            const size_t gc = n0 + (size_t)((sl >> 2) * 128 + wc * 32 + (sl & 3) * 8);
            *(short8*)&C[gr * (size_t)N + gc] = vv;
        }
    }

    // ---- epilogue (4): goodness (+ss) via MFMA on the ep tile ----
    short8 hfr[2];
#pragma unroll
    for (int ks = 0; ks < 2; ++ks) {
#pragma unroll
        for (int e = 0; e < 8; ++e) {
            const int gc = (int)n0 + ks * 128 + wc * 32 + hi * 8 + e;
            const float hv = (rsel < 10) ? hmat[rsel * 2048 + gc] : 0.f;
            hfr[ks][e] = (short)f2bf(hv);
        }
    }
    f32x4 gacc[8], ssacc[8];
#pragma unroll
    for (int rt = 0; rt < 8; ++rt) { gacc[rt] = (f32x4){0,0,0,0}; ssacc[rt] = (f32x4){0,0,0,0}; }
#pragma unroll
    for (int rt = 0; rt < 8; ++rt) {
#pragma unroll
        for (int ks = 0; ks < 2; ++ks) {
            short8 a2 = *(const short8*)&ep[(rt * 16 + rsel) * 64 + ((((ks << 2) + hi) ^ lsw) << 3)];
            gacc[rt] = __builtin_amdgcn_mfma_f32_16x16x32_bf16(a2, hfr[ks], gacc[rt], 0, 0, 0);
            if (MODE < 2)
                ssacc[rt] = __builtin_amdgcn_mfma_f32_16x16x32_bf16(a2, a2, ssacc[rt], 0, 0, 0);
        }
    }
    __syncthreads();   // all ep reads (C store + MFMA) complete before red overlays ldsA

    // ---- epilogue (5): cross-wave reduce in LDS, write-only global partials ----
    float* red = (float*)ldsA;   // [8 slices][128 rows][11] = 45056 B
    const int slice = wc * 2 + wr;
#pragma unroll
    for (int rt = 0; rt < 8; ++rt) {
        if (rsel < 10) {
#pragma unroll
            for (int rg = 0; rg < 4; ++rg)
                red[(slice * 128 + rt * 16 + hi * 4 + rg) * 11 + rsel] = gacc[rt][rg];
        }
        if (MODE < 2) {
            if ((rsel >> 2) == hi)
                red[(slice * 128 + rt * 16 + rsel) * 11 + 10] = ssacc[rt][rsel & 3];
        }
    }
    __syncthreads();
    for (int idx = tid; idx < 2816; idx += 512) {
        const int c = idx % 11;
        const int r2 = idx / 11;               // 0..255
        const int wrp = r2 >> 7, lrow = r2 & 127;
        float a = red[((0 + wrp) * 128 + lrow) * 11 + c]
                + red[((2 + wrp) * 128 + lrow) * 11 + c]
                + red[((4 + wrp) * 128 + lrow) * 11 + c]
                + red[((6 + wrp) * 128 + lrow) * 11 + c];
        const int grow = (int)m0 + ((lrow >> 6) << 7) + wrp * 64 + (lrow & 63);
        if (c < 10)
            good_p[((size_t)(MODE * 8 + tn) * 16384 + grow) * 10 + c] = a;
        else if (MODE < 2)
            ss_p[(size_t)tn * 16384 + grow] = a;
    }
}

// ---------------- s[r] = 1/(sqrt(sum_tn ss_p)+eps) ----------------
__global__ __launch_bounds__(256) void reduce_s_kernel(
    const float* __restrict__ ss_p, float* __restrict__ s)
{
    const int r = blockIdx.x * 256 + threadIdx.x;
    float a = 0.f;
#pragma unroll
    for (int slot = 0; slot < 8; ++slot) a += ss_p[(size_t)slot * 16384 + r];
    s[r] = 1.f / (sqrtf(a) + 1e-4f);
}

// ---------------- argmax over 24 summed class planes ----------------
__global__ __launch_bounds__(256) void argmax_kernel(
    const float* __restrict__ good_p, int* __restrict__ outp)
{
    const int r = blockIdx.x * 256 + threadIdx.x;
    float cls[10];
#pragma unroll
    for (int c = 0; c < 10; ++c) cls[c] = 0.f;
    for (int pl = 0; pl < 24; ++pl) {
        const float* tp = good_p + ((size_t)pl * 16384 + r) * 10;
#pragma unroll
        for (int c = 0; c < 10; ++c) cls[c] += tp[c];
    }
    float best = -3.4e38f;
    int bi = 0;
#pragma unroll
    for (int c = 0; c < 10; ++c) {
        if (cls[c] > best) { best = cls[c]; bi = c; }  // strict > : ties -> lowest
    }
    outp[r] = bi;
}

extern "C" void kernel_launch(void* const* d_in, const int* in_sizes, int n_in,
                              void* d_out, int out_size, void* d_ws, size_t ws_size,
                              hipStream_t stream)
{
    const float* x  = (const float*)d_in[0];
    const float* W0 = (const float*)d_in[1];
    const float* b0 = (const float*)d_in[2];
    const float* h0 = (const float*)d_in[3];
    const float* W1 = (const float*)d_in[4];
    const float* b1 = (const float*)d_in[5];
    const float* h1 = (const float*)d_in[6];
    const float* W2 = (const float*)d_in[7];
    const float* b2 = (const float*)d_in[8];
    const float* h2 = (const float*)d_in[9];
    int* out = (int*)d_out;

    const int M = 16384, N = 2048, K0 = 784, Kp0 = 896, D = 2048;

    char* ws = (char*)d_ws;
    size_t off = 0;
    auto alloc = [&](size_t bytes) -> void* {
        void* p = ws + off;
        off += (bytes + 255) & ~(size_t)255;
        return p;
    };
    u16* buf1  = (u16*)alloc((size_t)M * D * 2);     // x1 (layer-0 output)
    u16* buf2  = (u16*)alloc((size_t)M * D * 2);     // A0p, then x2
    u16* W0p   = (u16*)alloc((size_t)N * Kp0 * 2);
    u16* W1b   = (u16*)alloc((size_t)N * D * 2);
    u16* W2b   = (u16*)alloc((size_t)N * D * 2);
    float* good_p = (float*)alloc((size_t)24 * M * 10 * 4);  // 15.7 MB, write-once
    float* ss_p   = (float*)alloc((size_t)8 * M * 4);        // 512 KB
    float* svec   = (float*)alloc((size_t)M * 4);
    u16* A0p = buf2;  // 896-stride rows fit inside 2048-stride buffer

    convert_w_kernel<<<2048, 256, 0, stream>>>(W0, W0p, K0, Kp0, (long)N * Kp0);
    convert_w_kernel<<<2048, 256, 0, stream>>>(W1, W1b, D, D, (long)N * D);
    convert_w_kernel<<<2048, 256, 0, stream>>>(W2, W2b, D, D, (long)N * D);

    norm_x0_kernel<<<M, 256, 0, stream>>>(x, A0p, K0, Kp0);

    const int g256 = (M / 256) * (N / 256);  // 512 blocks, %8 == 0
    gemm256_fused<0><<<g256, 512, 0, stream>>>(A0p, W0p, b0, h0, nullptr, buf1,
                                               good_p, ss_p, N, Kp0);
    reduce_s_kernel<<<M / 256, 256, 0, stream>>>(ss_p, svec);
    gemm256_fused<1><<<g256, 512, 0, stream>>>(buf1, W1b, b1, h1, svec, buf2,
                                               good_p, ss_p, N, D);
    reduce_s_kernel<<<M / 256, 256, 0, stream>>>(ss_p, svec);
    gemm256_fused<2><<<g256, 512, 0, stream>>>(buf2, W2b, b2, h2, svec, nullptr,
                                               good_p, nullptr, N, D);
    argmax_kernel<<<M / 256, 256, 0, stream>>>(good_p, out);
}